// Round 19
// baseline (63.063 us; speedup 1.0000x reference)
//
#include <hip/hip_runtime.h>
#include <math.h>

typedef unsigned short u16;
typedef unsigned int uint32;
typedef __attribute__((ext_vector_type(4))) float f32x4;
typedef __attribute__((ext_vector_type(4))) unsigned int u32x4;
typedef __bf16 bf16x8 __attribute__((ext_vector_type(8)));

#define MFMA16(a,b,c) __builtin_amdgcn_mfma_f32_16x16x32_bf16((a),(b),(c),0,0,0)

typedef const __attribute__((address_space(1))) unsigned GU;
typedef __attribute__((address_space(3))) unsigned LU;
__device__ __forceinline__ void gl_lds16(const void* g, void* l) {
    // dest = wave-uniform LDS base + lane*16 ; src = per-lane global address
    __builtin_amdgcn_global_load_lds((GU*)g, (LU*)l, 16, 0, 0);
}

__device__ __forceinline__ u16 f2b(float f) {
    __bf16 h = (__bf16)f;             // RNE
    return __builtin_bit_cast(u16, h);
}
__device__ __forceinline__ float b2f(u16 u) {
    unsigned v = (unsigned)u << 16;
    return __builtin_bit_cast(float, v);
}

// pinned-count asm primitives
__device__ __forceinline__ void agload4(f32x4& d, const float* p) {
    asm volatile("global_load_dwordx4 %0, %1, off" : "=&v"(d) : "v"(p) : "memory");
}
__device__ __forceinline__ void dsr(bf16x8& d, uint32 a) {
    u32x4 tmp;
    asm volatile("ds_read_b128 %0, %1" : "=&v"(tmp) : "v"(a) : "memory");
    d = __builtin_bit_cast(bf16x8, tmp);
}
#define WAITVM_I(n) asm volatile("s_waitcnt vmcnt(" #n ")" ::: "memory")
#define WAITVM(n) WAITVM_I(n)

// ---------- 1. wtrans: W[1024][64] f32 x3 -> fragment-native Wt2 ----------
// Wt2 u16, frag index fi = kstep*48 + cg*4 + kh*2 + hl ; frag = [kg=4][r=16][e=8] (1KB)
__global__ __launch_bounds__(128) void wtrans_kernel(
    const float* __restrict__ Wq, const float* __restrict__ Wk,
    const float* __restrict__ Wv, u16* __restrict__ Wt2)
{
    const int n = blockIdx.x;                         // 0..191
    const float* W = (n < 64) ? Wq : ((n < 128) ? Wk : Wv);
    const int nc = n & 63, cg = n >> 4, r = n & 15;
    const int t = threadIdx.x;                        // 0..127
    const int k0 = t * 8;
    const int kstep = k0 >> 6, kh = (k0 >> 5) & 1, kg = (k0 >> 3) & 3;
    u16 hh[8], ll[8];
#pragma unroll
    for (int i = 0; i < 8; ++i) {
        const float a = W[(size_t)(k0 + i) * 64 + nc];
        hh[i] = f2b(a);
        ll[i] = f2b(a - b2f(hh[i]));
    }
    const size_t fi = (size_t)kstep * 48 + (size_t)cg * 4 + (size_t)kh * 2;   // hl=0
    u16* dst = Wt2 + fi * 512 + kg * 128 + r * 8;
    uint4 vh, vl;
    vh.x = (uint)hh[0] | ((uint)hh[1] << 16); vh.y = (uint)hh[2] | ((uint)hh[3] << 16);
    vh.z = (uint)hh[4] | ((uint)hh[5] << 16); vh.w = (uint)hh[6] | ((uint)hh[7] << 16);
    vl.x = (uint)ll[0] | ((uint)ll[1] << 16); vl.y = (uint)ll[2] | ((uint)ll[3] << 16);
    vl.z = (uint)ll[4] | ((uint)ll[5] << 16); vl.w = (uint)ll[6] | ((uint)ll[7] << 16);
    *(uint4*)dst         = vh;      // hl=0
    *(uint4*)(dst + 512) = vl;      // hl=1
}

// ---------- 2. fused QKV proj: kq-split waves, zero-redundancy LDS reads ----------
// 256 blocks x 512 thr (8 waves). Wave w = (kq=w&1 K-half, nt=w>>1 cg-triple). BM=32,
// 32 rows per wave. Each wave stages AND reads exactly its own 6 frags/step (block
// total 48 ds_read_b128/step, was 96 with row-split). 18 MFMA/wave/step, 10 vm-ops/
// wave/step -> r14 counted-vmcnt table unchanged. Split-K partials merged via LDS.
__global__ __launch_bounds__(512) void proj_kernel(
    const float* __restrict__ x, const u16* __restrict__ Wt2,
    u16* __restrict__ Qhi, u16* __restrict__ Qlo,
    u16* __restrict__ Khi, u16* __restrict__ Klo, u16* __restrict__ Vt)
{
    __shared__ u16 WB[3][48][512];   // 144 KB triple-buffered W chunk (frag-native)
    __shared__ u16 vs[32][72];

    const int t = threadIdx.x, w = t >> 6, lane = t & 63;
    const int lo = lane & 15, hi = lane >> 4;
    const int kq = w & 1, nt = w >> 1;
    const int row0 = blockIdx.x * 32;

    f32x4 acc[2][3];
#pragma unroll
    for (int rh = 0; rh < 2; ++rh)
#pragma unroll
        for (int i = 0; i < 3; ++i) acc[rh][i] = (f32x4){0.f, 0.f, 0.f, 0.f};

    const float* xrow0 = x + (size_t)(row0 + lo) * 1024 + kq * 32 + hi * 8;
    const float* xrow1 = x + (size_t)(row0 + 16 + lo) * 1024 + kq * 32 + hi * 8;
    const uint32 ldsbase = (uint32)(size_t)(LU*)(&WB[0][0][0]);

    f32x4 xr[3][4];

    auto stageS = [&](int buf, int s) {      // 6 gl_lds: wave's OWN frags of step s
#pragma unroll
        for (int i = 0; i < 3; ++i)
#pragma unroll
            for (int hl = 0; hl < 2; ++hl) {
                const size_t fi = (size_t)s * 48 + (size_t)(nt * 3 + i) * 4
                                + (size_t)kq * 2 + hl;
                gl_lds16(Wt2 + fi * 512 + lane * 8, &WB[buf][w * 6 + i * 2 + hl][0]);
            }
    };
    auto issueX = [&](f32x4 (&xv)[4], int s) {   // 4 asm global_load_dwordx4
        agload4(xv[0], xrow0 + s * 64);
        agload4(xv[1], xrow0 + s * 64 + 4);
        agload4(xv[2], xrow1 + s * 64);
        agload4(xv[3], xrow1 + s * 64 + 4);
    };
    auto computeS = [&](int buf, const f32x4 (&xv)[4]) {
        bf16x8 wf[6];
        const uint32 bb = ldsbase + (uint32)buf * 49152u
                        + (uint32)(w * 6) * 1024u + (uint32)lane * 16u;
#pragma unroll
        for (int j = 0; j < 6; ++j)
            dsr(wf[j], bb + (uint32)j * 1024u);
        asm volatile("s_waitcnt lgkmcnt(0)" ::: "memory");
        __builtin_amdgcn_sched_barrier(0);
        __builtin_amdgcn_s_setprio(1);
#pragma unroll
        for (int rh = 0; rh < 2; ++rh) {
            bf16x8 ah, al;
#pragma unroll
            for (int e = 0; e < 4; ++e) {
                { float v = xv[rh * 2][e];     __bf16 hb = (__bf16)v; ah[e] = hb;     al[e] = (__bf16)(v - (float)hb); }
                { float v = xv[rh * 2 + 1][e]; __bf16 hb = (__bf16)v; ah[4 + e] = hb; al[4 + e] = (__bf16)(v - (float)hb); }
            }
#pragma unroll
            for (int i = 0; i < 3; ++i) {
                const bf16x8 wh = wf[i * 2 + 0];
                const bf16x8 wl = wf[i * 2 + 1];
                acc[rh][i] = MFMA16(ah, wh, acc[rh][i]);
                acc[rh][i] = MFMA16(ah, wl, acc[rh][i]);
                acc[rh][i] = MFMA16(al, wh, acc[rh][i]);
            }
        }
        __builtin_amdgcn_s_setprio(0);
    };

    // prologue: S0, X0, S1, X1  (20 loads in flight)
    stageS(0, 0);
    issueX(xr[0], 0);
    stageS(1, 1);
    issueX(xr[1], 1);

#define PSTEP(S_, N1_)                                                  \
    do {                                                                \
        WAITVM(N1_);                                                    \
        __builtin_amdgcn_sched_barrier(0);                              \
        __builtin_amdgcn_s_barrier();                                   \
        __builtin_amdgcn_sched_barrier(0);                              \
        if ((S_) + 2 <= 15) {                                           \
            stageS(((S_) + 2) % 3, (S_) + 2);                           \
            issueX(xr[((S_) + 2) % 3], (S_) + 2);                       \
        }                                                               \
        computeS((S_) % 3, xr[(S_) % 3]);                               \
    } while (0)

    PSTEP(0, 10);  PSTEP(1, 10);  PSTEP(2, 10);  PSTEP(3, 10);
    PSTEP(4, 10);  PSTEP(5, 10);  PSTEP(6, 10);  PSTEP(7, 10);
    PSTEP(8, 10);  PSTEP(9, 10);  PSTEP(10, 10); PSTEP(11, 10);
    PSTEP(12, 10); PSTEP(13, 10); PSTEP(14, 10); PSTEP(15, 0);
#undef PSTEP

    // ---- cross-kq merge: kq=1 publishes partials via LDS overlay on WB ----
    float* PR = (float*)&WB[0][0][0];     // 24 KB overlay (staging complete)
    __syncthreads();                      // all computeS reads of WB done
    if (kq == 1) {
#pragma unroll
        for (int rh = 0; rh < 2; ++rh)
#pragma unroll
            for (int i = 0; i < 3; ++i)
                *(f32x4*)&PR[((nt * 6) + rh * 3 + i) * 256 + lane * 4] = acc[rh][i];
    }
    __syncthreads();
    if (kq == 0) {
#pragma unroll
        for (int rh = 0; rh < 2; ++rh)
#pragma unroll
            for (int i = 0; i < 3; ++i) {
                const f32x4 o = *(const f32x4*)&PR[((nt * 6) + rh * 3 + i) * 256 + lane * 4];
                acc[rh][i] += o;
            }
        // epilogue: Q,K -> hi/lo global; V -> LDS tile (kq=0 waves only)
#pragma unroll
        for (int i = 0; i < 3; ++i) {
            const int cg = nt * 3 + i;
#pragma unroll
            for (int rh = 0; rh < 2; ++rh)
#pragma unroll
                for (int r = 0; r < 4; ++r) {
                    const float v = acc[rh][i][r];
                    const int row = row0 + rh * 16 + hi * 4 + r;
                    const u16 h = f2b(v);
                    if (cg < 4) {
                        Qhi[(size_t)row * 64 + cg * 16 + lo] = h;
                        Qlo[(size_t)row * 64 + cg * 16 + lo] = f2b(v - b2f(h));
                    } else if (cg < 8) {
                        Khi[(size_t)row * 64 + (cg - 4) * 16 + lo] = h;
                        Klo[(size_t)row * 64 + (cg - 4) * 16 + lo] = f2b(v - b2f(h));
                    } else {
                        vs[rh * 16 + hi * 4 + r][(cg - 8) * 16 + lo] = h;
                    }
                }
        }
    }
    __syncthreads();
    {   // Vt[b][d][tok] : 64 dims x 32 tokens, 512 threads -> 4 tokens each
        const int bb = row0 >> 11, tok0 = row0 & 2047;
        const int d = t >> 3, part = t & 7;
        u16 tmp[4];
#pragma unroll
        for (int i = 0; i < 4; ++i) tmp[i] = vs[part * 4 + i][d];
        uint2 v2;
        v2.x = (uint)tmp[0] | ((uint)tmp[1] << 16);
        v2.y = (uint)tmp[2] | ((uint)tmp[3] << 16);
        *(uint2*)(Vt + (size_t)bb * 131072 + (size_t)d * 2048 + tok0 + part * 4) = v2;
    }
}

// ---------- 3. flash attention: paired q-tiles, 8-wave split-K, no-max softmax ----------
// grid (64,4) x 512 thr. Block handles q-tiles 127-pi (heavy) then pi (light) -> 256
// equal-work blocks. Per-lane ls accumulation; single shfl-reduce per phase.
__global__ __launch_bounds__(512, 2) void attn_kernel(
    const u16* __restrict__ Qhi, const u16* __restrict__ Qlo,
    const u16* __restrict__ Khi, const u16* __restrict__ Klo,
    const u16* __restrict__ Vt, float* __restrict__ out)
{
    __shared__ u16 P[8][16 * 64];       // per-wave P tile, XOR-swizzled
    __shared__ float OA[8][16][64];     // per-wave partial O
    __shared__ float LS[8][16];         // per-wave partial ls

    const int pi = blockIdx.x, b = blockIdx.y;
    const int t = threadIdx.x, w = t >> 6, l = t & 63;
    const int lo = l & 15, hi = l >> 4;

    const u16* Qh = Qhi + (size_t)b * 131072;
    const u16* Ql = Qlo + (size_t)b * 131072;
    const u16* Kh = Khi + (size_t)b * 131072;
    const u16* Kl = Klo + (size_t)b * 131072;
    const u16* V  = Vt  + (size_t)b * 131072;

    u16* Pw = P[w];

#pragma unroll 1
    for (int phase = 0; phase < 2; ++phase) {
        const int p = phase ? pi : (127 - pi);
        const int q0 = p * 16;
        const int nt = (p >> 2) + 1;

        bf16x8 aqh[2], aql[2];
#pragma unroll
        for (int s = 0; s < 2; ++s) {
            aqh[s] = *(const bf16x8*)(Qh + (size_t)(q0 + lo) * 64 + s * 32 + hi * 8);
            aql[s] = *(const bf16x8*)(Ql + (size_t)(q0 + lo) * 64 + s * 32 + hi * 8);
        }

        f32x4 acc[4];
        float ls[4];                      // PER-LANE partial sums (reduced once per phase)
#pragma unroll
        for (int r = 0; r < 4; ++r) { acc[r] = (f32x4){0.f,0.f,0.f,0.f}; ls[r] = 0.f; }

        bf16x8 kh[4][2], kl[4][2];
        auto loadK = [&](int j0) {
#pragma unroll
            for (int kg = 0; kg < 4; ++kg)
#pragma unroll
                for (int s = 0; s < 2; ++s) {
                    const size_t off = (size_t)(j0 + kg * 16 + lo) * 64 + s * 32 + hi * 8;
                    kh[kg][s] = *(const bf16x8*)(Kh + off);
                    kl[kg][s] = *(const bf16x8*)(Kl + off);
                }
        };

        if (w < nt) loadK(w * 64);
#pragma unroll 1
        for (int j = w; j < nt; j += 8) {
            const int j0 = j * 64;
            bf16x8 bv[4][2];
#pragma unroll
            for (int dg = 0; dg < 4; ++dg)
#pragma unroll
                for (int s = 0; s < 2; ++s)
                    bv[dg][s] = *(const bf16x8*)(V + (size_t)(dg * 16 + lo) * 2048 + j0 + s * 32 + hi * 8);

            f32x4 S[4];
            const f32x4 zf = (f32x4){0.f,0.f,0.f,0.f};
            __builtin_amdgcn_s_setprio(1);
#pragma unroll
            for (int kg = 0; kg < 4; ++kg) {
                f32x4 sv = zf;
                sv = MFMA16(aqh[0], kh[kg][0], sv);
                sv = MFMA16(aqh[1], kh[kg][1], sv);
                sv = MFMA16(aqh[0], kl[kg][0], sv);
                sv = MFMA16(aqh[1], kl[kg][1], sv);
                sv = MFMA16(aql[0], kh[kg][0], sv);
                sv = MFMA16(aql[1], kh[kg][1], sv);
                S[kg] = sv;
            }
            __builtin_amdgcn_s_setprio(0);

            if (j + 8 < nt) loadK((j + 8) * 64);   // issue-early: flies during softmax+PV

            const bool dm = (j == nt - 1);
#pragma unroll
            for (int r = 0; r < 4; ++r) {
                const int row = q0 + hi * 4 + r;
                float sv0 = S[0][r], sv1 = S[1][r], sv2 = S[2][r], sv3 = S[3][r];
                if (dm) {
                    sv0 = (j0 +      lo > row) ? -INFINITY : sv0;
                    sv1 = (j0 + 16 + lo > row) ? -INFINITY : sv1;
                    sv2 = (j0 + 32 + lo > row) ? -INFINITY : sv2;
                    sv3 = (j0 + 48 + lo > row) ? -INFINITY : sv3;
                }
                const u16 u0 = f2b(__expf(sv0)), u1 = f2b(__expf(sv1));
                const u16 u2 = f2b(__expf(sv2)), u3 = f2b(__expf(sv3));
                ls[r] += (b2f(u0) + b2f(u1)) + (b2f(u2) + b2f(u3));   // no shfl here
                const int rowL = hi * 4 + r;
                const int base = rowL * 64;
                const int sw = rowL & 7;
                Pw[base + (((0 + (lo >> 3)) ^ sw) << 3) + (lo & 7)] = u0;
                Pw[base + (((2 + (lo >> 3)) ^ sw) << 3) + (lo & 7)] = u1;
                Pw[base + (((4 + (lo >> 3)) ^ sw) << 3) + (lo & 7)] = u2;
                Pw[base + (((6 + (lo >> 3)) ^ sw) << 3) + (lo & 7)] = u3;
            }
            // same-wave DS producer/consumer: no barrier needed
            const bf16x8 pa0 = *(const bf16x8*)&Pw[lo * 64 + (((hi    ) ^ (lo & 7)) << 3)];
            const bf16x8 pa1 = *(const bf16x8*)&Pw[lo * 64 + (((hi + 4) ^ (lo & 7)) << 3)];
            __builtin_amdgcn_s_setprio(1);
#pragma unroll
            for (int dg = 0; dg < 4; ++dg) {
                acc[dg] = MFMA16(pa0, bv[dg][0], acc[dg]);
                acc[dg] = MFMA16(pa1, bv[dg][1], acc[dg]);
            }
            __builtin_amdgcn_s_setprio(0);
        }

        // ---- once-per-phase ls reduce over the 16 lanes sharing a row ----
#pragma unroll
        for (int r = 0; r < 4; ++r) {
#pragma unroll
            for (int msk = 8; msk; msk >>= 1) ls[r] += __shfl_xor(ls[r], msk, 64);
        }

        // ---- write per-wave partials (zeros for idle waves) ----
#pragma unroll
        for (int r = 0; r < 4; ++r) {
            if (lo == 0) LS[w][hi * 4 + r] = ls[r];
#pragma unroll
            for (int dg = 0; dg < 4; ++dg) OA[w][hi * 4 + r][dg * 16 + lo] = acc[dg][r];
        }
        __syncthreads();

        // ---- merge: plain sums over the 8 waves ----
        {
            const int row = t >> 5, c0 = (t & 31) * 2;
            float s0 = 0.f, s1 = 0.f, Lt = 0.f;
#pragma unroll
            for (int wv = 0; wv < 8; ++wv) {
                s0 += OA[wv][row][c0];
                s1 += OA[wv][row][c0 + 1];
                Lt += LS[wv][row];
            }
            const float inv = 0.125f / Lt;
            float2 o = make_float2(s0 * inv, s1 * inv);
            *(float2*)(out + ((size_t)b * 2048 + q0 + row) * 64 + c0) = o;
        }
        __syncthreads();   // protect OA/LS reuse by next phase
    }
}

extern "C" void kernel_launch(void* const* d_in, const int* in_sizes, int n_in,
                              void* d_out, int out_size, void* d_ws, size_t ws_size,
                              hipStream_t stream) {
    const float* x  = (const float*)d_in[0];
    const float* Wq = (const float*)d_in[1];
    const float* Wk = (const float*)d_in[2];
    const float* Wv = (const float*)d_in[3];
    float* outp = (float*)d_out;

    u16* Wt2 = (u16*)d_ws;               // 16*48*512 = 393216 u16 (768 KB)
    u16* Qhi = Wt2 + 393216;             // 8192*64 each
    u16* Qlo = Qhi + 524288;
    u16* Khi = Qlo + 524288;
    u16* Klo = Khi + 524288;
    u16* Vt  = Klo + 524288;             // [4][64][2048]

    wtrans_kernel<<<dim3(192), dim3(128), 0, stream>>>(Wq, Wk, Wv, Wt2);
    proj_kernel<<<dim3(256), dim3(512), 0, stream>>>(x, Wt2, Qhi, Qlo, Khi, Klo, Vt);
    attn_kernel<<<dim3(64, 4), dim3(512), 0, stream>>>(Qhi, Qlo, Khi, Klo, Vt, outp);
}

// Round 20
// 61.370 us; speedup vs baseline: 1.0276x; 1.0276x over previous
//
#include <hip/hip_runtime.h>
#include <math.h>

typedef unsigned short u16;
typedef unsigned int uint32;
typedef __attribute__((ext_vector_type(4))) float f32x4;
typedef __attribute__((ext_vector_type(4))) unsigned int u32x4;
typedef __bf16 bf16x8 __attribute__((ext_vector_type(8)));

#define MFMA16(a,b,c) __builtin_amdgcn_mfma_f32_16x16x32_bf16((a),(b),(c),0,0,0)

typedef const __attribute__((address_space(1))) unsigned GU;
typedef __attribute__((address_space(3))) unsigned LU;
__device__ __forceinline__ void gl_lds16(const void* g, void* l) {
    // dest = wave-uniform LDS base + lane*16 ; src = per-lane global address
    __builtin_amdgcn_global_load_lds((GU*)g, (LU*)l, 16, 0, 0);
}

__device__ __forceinline__ u16 f2b(float f) {
    __bf16 h = (__bf16)f;             // RNE
    return __builtin_bit_cast(u16, h);
}
__device__ __forceinline__ float b2f(u16 u) {
    unsigned v = (unsigned)u << 16;
    return __builtin_bit_cast(float, v);
}

// pinned-count asm primitives
__device__ __forceinline__ void agload4(f32x4& d, const float* p) {
    asm volatile("global_load_dwordx4 %0, %1, off" : "=&v"(d) : "v"(p) : "memory");
}
__device__ __forceinline__ void dsr(bf16x8& d, uint32 a) {
    u32x4 tmp;
    asm volatile("ds_read_b128 %0, %1" : "=&v"(tmp) : "v"(a) : "memory");
    d = __builtin_bit_cast(bf16x8, tmp);
}
#define WAITVM_I(n) asm volatile("s_waitcnt vmcnt(" #n ")" ::: "memory")
#define WAITVM(n) WAITVM_I(n)

// ---------- 1. wtrans: W[1024][64] f32 x3 -> fragment-native Wt2 ----------
// Wt2 u16, frag index fi = kstep*48 + cg*4 + kh*2 + hl ; frag = [kg=4][r=16][e=8] (1KB)
__global__ __launch_bounds__(128) void wtrans_kernel(
    const float* __restrict__ Wq, const float* __restrict__ Wk,
    const float* __restrict__ Wv, u16* __restrict__ Wt2)
{
    const int n = blockIdx.x;                         // 0..191
    const float* W = (n < 64) ? Wq : ((n < 128) ? Wk : Wv);
    const int nc = n & 63, cg = n >> 4, r = n & 15;
    const int t = threadIdx.x;                        // 0..127
    const int k0 = t * 8;
    const int kstep = k0 >> 6, kh = (k0 >> 5) & 1, kg = (k0 >> 3) & 3;
    u16 hh[8], ll[8];
#pragma unroll
    for (int i = 0; i < 8; ++i) {
        const float a = W[(size_t)(k0 + i) * 64 + nc];
        hh[i] = f2b(a);
        ll[i] = f2b(a - b2f(hh[i]));
    }
    const size_t fi = (size_t)kstep * 48 + (size_t)cg * 4 + (size_t)kh * 2;   // hl=0
    u16* dst = Wt2 + fi * 512 + kg * 128 + r * 8;
    uint4 vh, vl;
    vh.x = (uint)hh[0] | ((uint)hh[1] << 16); vh.y = (uint)hh[2] | ((uint)hh[3] << 16);
    vh.z = (uint)hh[4] | ((uint)hh[5] << 16); vh.w = (uint)hh[6] | ((uint)hh[7] << 16);
    vl.x = (uint)ll[0] | ((uint)ll[1] << 16); vl.y = (uint)ll[2] | ((uint)ll[3] << 16);
    vl.z = (uint)ll[4] | ((uint)ll[5] << 16); vl.w = (uint)ll[6] | ((uint)ll[7] << 16);
    *(uint4*)dst         = vh;      // hl=0
    *(uint4*)(dst + 512) = vl;      // hl=1
}

// ---------- 2. fused QKV proj: triple-buffered counted-vmcnt pipeline + setprio ----------
__global__ __launch_bounds__(512) void proj_kernel(
    const float* __restrict__ x, const u16* __restrict__ Wt2,
    u16* __restrict__ Qhi, u16* __restrict__ Qlo,
    u16* __restrict__ Khi, u16* __restrict__ Klo, u16* __restrict__ Vt)
{
    __shared__ u16 WB[3][48][512];   // 144 KB triple-buffered W chunk (frag-native)
    __shared__ u16 vs[32][72];

    const int t = threadIdx.x, w = t >> 6, lane = t & 63;
    const int lo = lane & 15, hi = lane >> 4;
    const int mh = w & 1, nt = w >> 1;
    const int row0 = blockIdx.x * 32;

    f32x4 acc[3];
#pragma unroll
    for (int i = 0; i < 3; ++i) acc[i] = (f32x4){0.f, 0.f, 0.f, 0.f};

    const float* xrow = x + (size_t)(row0 + mh * 16 + lo) * 1024 + hi * 8;
    const uint32 ldsbase = (uint32)(size_t)(LU*)(&WB[0][0][0]);

    f32x4 xr[3][4];

    auto stageS = [&](int buf, int s) {      // 6 gl_lds: frags j = w*6 .. w*6+5 of step s
#pragma unroll
        for (int i = 0; i < 6; ++i)
            gl_lds16(Wt2 + ((size_t)s * 48 + w * 6 + i) * 512 + lane * 8,
                     &WB[buf][w * 6 + i][0]);
    };
    auto issueX = [&](f32x4 (&xv)[4], int s) {   // 4 asm global_load_dwordx4
#pragma unroll
        for (int kh = 0; kh < 2; ++kh)
#pragma unroll
            for (int j = 0; j < 2; ++j)
                agload4(xv[kh * 2 + j], xrow + s * 64 + kh * 32 + j * 4);
    };
    auto computeS = [&](int buf, const f32x4 (&xv)[4]) {
        bf16x8 wf[12];
        const uint32 bb = ldsbase + (uint32)buf * 49152u
                        + (uint32)(nt * 12) * 1024u + (uint32)lane * 16u;
#pragma unroll
        for (int j = 0; j < 12; ++j)
            dsr(wf[j], bb + (uint32)j * 1024u);
        asm volatile("s_waitcnt lgkmcnt(0)" ::: "memory");
        __builtin_amdgcn_sched_barrier(0);
        __builtin_amdgcn_s_setprio(1);
#pragma unroll
        for (int kh = 0; kh < 2; ++kh) {
            bf16x8 ah, al;
#pragma unroll
            for (int e = 0; e < 4; ++e) {
                { float v = xv[kh * 2][e];     __bf16 hb = (__bf16)v; ah[e] = hb;     al[e] = (__bf16)(v - (float)hb); }
                { float v = xv[kh * 2 + 1][e]; __bf16 hb = (__bf16)v; ah[4 + e] = hb; al[4 + e] = (__bf16)(v - (float)hb); }
            }
#pragma unroll
            for (int i = 0; i < 3; ++i) {
                const bf16x8 wh = wf[i * 4 + kh * 2 + 0];
                const bf16x8 wl = wf[i * 4 + kh * 2 + 1];
                acc[i] = MFMA16(ah, wh, acc[i]);
                acc[i] = MFMA16(ah, wl, acc[i]);
                acc[i] = MFMA16(al, wh, acc[i]);
            }
        }
        __builtin_amdgcn_s_setprio(0);
    };

    // prologue: S0, X0, S1, X1  (20 loads in flight)
    stageS(0, 0);
    issueX(xr[0], 0);
    stageS(1, 1);
    issueX(xr[1], 1);

#define PSTEP(S_, N1_)                                                  \
    do {                                                                \
        WAITVM(N1_);                                                    \
        __builtin_amdgcn_sched_barrier(0);                              \
        __builtin_amdgcn_s_barrier();                                   \
        __builtin_amdgcn_sched_barrier(0);                              \
        if ((S_) + 2 <= 15) {                                           \
            stageS(((S_) + 2) % 3, (S_) + 2);                           \
            issueX(xr[((S_) + 2) % 3], (S_) + 2);                       \
        }                                                               \
        computeS((S_) % 3, xr[(S_) % 3]);                               \
    } while (0)

    PSTEP(0, 10);  PSTEP(1, 10);  PSTEP(2, 10);  PSTEP(3, 10);
    PSTEP(4, 10);  PSTEP(5, 10);  PSTEP(6, 10);  PSTEP(7, 10);
    PSTEP(8, 10);  PSTEP(9, 10);  PSTEP(10, 10); PSTEP(11, 10);
    PSTEP(12, 10); PSTEP(13, 10); PSTEP(14, 10); PSTEP(15, 0);
#undef PSTEP

    // epilogue: Q,K -> hi/lo global; V -> LDS tile then transposed global
#pragma unroll
    for (int i = 0; i < 3; ++i) {
        const int cg = nt * 3 + i;
#pragma unroll
        for (int r = 0; r < 4; ++r) {
            const float v = acc[i][r];
            const int row = row0 + mh * 16 + hi * 4 + r;
            const u16 h = f2b(v);
            if (cg < 4) {
                Qhi[(size_t)row * 64 + cg * 16 + lo] = h;
                Qlo[(size_t)row * 64 + cg * 16 + lo] = f2b(v - b2f(h));
            } else if (cg < 8) {
                Khi[(size_t)row * 64 + (cg - 4) * 16 + lo] = h;
                Klo[(size_t)row * 64 + (cg - 4) * 16 + lo] = f2b(v - b2f(h));
            } else {
                vs[mh * 16 + hi * 4 + r][(cg - 8) * 16 + lo] = h;
            }
        }
    }
    __syncthreads();
    {   // Vt[b][d][tok] : 64 dims x 32 tokens, 512 threads -> 4 tokens each
        const int bb = row0 >> 11, tok0 = row0 & 2047;
        const int d = t >> 3, part = t & 7;
        u16 tmp[4];
#pragma unroll
        for (int i = 0; i < 4; ++i) tmp[i] = vs[part * 4 + i][d];
        uint2 v2;
        v2.x = (uint)tmp[0] | ((uint)tmp[1] << 16);
        v2.y = (uint)tmp[2] | ((uint)tmp[3] << 16);
        *(uint2*)(Vt + (size_t)bb * 131072 + (size_t)d * 2048 + tok0 + part * 4) = v2;
    }
}

// ---------- 3. flash attention: paired q-tiles, 8-wave split-K, no-max softmax ----------
// grid (64,4) x 512 thr. Block handles q-tiles 127-pi (heavy) then pi (light) -> 256
// equal-work blocks (r15/r17 lesson: this balanced decomposition beats both finer and
// coarser splits). Per-lane ls accumulation; single shfl-reduce per phase.
__global__ __launch_bounds__(512, 2) void attn_kernel(
    const u16* __restrict__ Qhi, const u16* __restrict__ Qlo,
    const u16* __restrict__ Khi, const u16* __restrict__ Klo,
    const u16* __restrict__ Vt, float* __restrict__ out)
{
    __shared__ u16 P[8][16 * 64];       // per-wave P tile, XOR-swizzled
    __shared__ float OA[8][16][64];     // per-wave partial O
    __shared__ float LS[8][16];         // per-wave partial ls

    const int pi = blockIdx.x, b = blockIdx.y;
    const int t = threadIdx.x, w = t >> 6, l = t & 63;
    const int lo = l & 15, hi = l >> 4;

    const u16* Qh = Qhi + (size_t)b * 131072;
    const u16* Ql = Qlo + (size_t)b * 131072;
    const u16* Kh = Khi + (size_t)b * 131072;
    const u16* Kl = Klo + (size_t)b * 131072;
    const u16* V  = Vt  + (size_t)b * 131072;

    u16* Pw = P[w];

#pragma unroll 1
    for (int phase = 0; phase < 2; ++phase) {
        const int p = phase ? pi : (127 - pi);
        const int q0 = p * 16;
        const int nt = (p >> 2) + 1;

        bf16x8 aqh[2], aql[2];
#pragma unroll
        for (int s = 0; s < 2; ++s) {
            aqh[s] = *(const bf16x8*)(Qh + (size_t)(q0 + lo) * 64 + s * 32 + hi * 8);
            aql[s] = *(const bf16x8*)(Ql + (size_t)(q0 + lo) * 64 + s * 32 + hi * 8);
        }

        f32x4 acc[4];
        float ls[4];                      // PER-LANE partial sums (reduced once per phase)
#pragma unroll
        for (int r = 0; r < 4; ++r) { acc[r] = (f32x4){0.f,0.f,0.f,0.f}; ls[r] = 0.f; }

        bf16x8 kh[4][2], kl[4][2];
        auto loadK = [&](int j0) {
#pragma unroll
            for (int kg = 0; kg < 4; ++kg)
#pragma unroll
                for (int s = 0; s < 2; ++s) {
                    const size_t off = (size_t)(j0 + kg * 16 + lo) * 64 + s * 32 + hi * 8;
                    kh[kg][s] = *(const bf16x8*)(Kh + off);
                    kl[kg][s] = *(const bf16x8*)(Kl + off);
                }
        };

        if (w < nt) loadK(w * 64);
#pragma unroll 1
        for (int j = w; j < nt; j += 8) {
            const int j0 = j * 64;
            bf16x8 bv[4][2];
#pragma unroll
            for (int dg = 0; dg < 4; ++dg)
#pragma unroll
                for (int s = 0; s < 2; ++s)
                    bv[dg][s] = *(const bf16x8*)(V + (size_t)(dg * 16 + lo) * 2048 + j0 + s * 32 + hi * 8);

            f32x4 S[4];
            const f32x4 zf = (f32x4){0.f,0.f,0.f,0.f};
            __builtin_amdgcn_s_setprio(1);
#pragma unroll
            for (int kg = 0; kg < 4; ++kg) {
                f32x4 sv = zf;
                sv = MFMA16(aqh[0], kh[kg][0], sv);
                sv = MFMA16(aqh[1], kh[kg][1], sv);
                sv = MFMA16(aqh[0], kl[kg][0], sv);
                sv = MFMA16(aqh[1], kl[kg][1], sv);
                sv = MFMA16(aql[0], kh[kg][0], sv);
                sv = MFMA16(aql[1], kh[kg][1], sv);
                S[kg] = sv;
            }
            __builtin_amdgcn_s_setprio(0);

            if (j + 8 < nt) loadK((j + 8) * 64);   // issue-early: flies during softmax+PV

            const bool dm = (j == nt - 1);
#pragma unroll
            for (int r = 0; r < 4; ++r) {
                const int row = q0 + hi * 4 + r;
                float sv0 = S[0][r], sv1 = S[1][r], sv2 = S[2][r], sv3 = S[3][r];
                if (dm) {
                    sv0 = (j0 +      lo > row) ? -INFINITY : sv0;
                    sv1 = (j0 + 16 + lo > row) ? -INFINITY : sv1;
                    sv2 = (j0 + 32 + lo > row) ? -INFINITY : sv2;
                    sv3 = (j0 + 48 + lo > row) ? -INFINITY : sv3;
                }
                const u16 u0 = f2b(__expf(sv0)), u1 = f2b(__expf(sv1));
                const u16 u2 = f2b(__expf(sv2)), u3 = f2b(__expf(sv3));
                ls[r] += (b2f(u0) + b2f(u1)) + (b2f(u2) + b2f(u3));   // no shfl here
                const int rowL = hi * 4 + r;
                const int base = rowL * 64;
                const int sw = rowL & 7;
                Pw[base + (((0 + (lo >> 3)) ^ sw) << 3) + (lo & 7)] = u0;
                Pw[base + (((2 + (lo >> 3)) ^ sw) << 3) + (lo & 7)] = u1;
                Pw[base + (((4 + (lo >> 3)) ^ sw) << 3) + (lo & 7)] = u2;
                Pw[base + (((6 + (lo >> 3)) ^ sw) << 3) + (lo & 7)] = u3;
            }
            // same-wave DS producer/consumer: no barrier needed
            const bf16x8 pa0 = *(const bf16x8*)&Pw[lo * 64 + (((hi    ) ^ (lo & 7)) << 3)];
            const bf16x8 pa1 = *(const bf16x8*)&Pw[lo * 64 + (((hi + 4) ^ (lo & 7)) << 3)];
            __builtin_amdgcn_s_setprio(1);
#pragma unroll
            for (int dg = 0; dg < 4; ++dg) {
                acc[dg] = MFMA16(pa0, bv[dg][0], acc[dg]);
                acc[dg] = MFMA16(pa1, bv[dg][1], acc[dg]);
            }
            __builtin_amdgcn_s_setprio(0);
        }

        // ---- once-per-phase ls reduce over the 16 lanes sharing a row ----
#pragma unroll
        for (int r = 0; r < 4; ++r) {
#pragma unroll
            for (int msk = 8; msk; msk >>= 1) ls[r] += __shfl_xor(ls[r], msk, 64);
        }

        // ---- write per-wave partials (zeros for idle waves) ----
#pragma unroll
        for (int r = 0; r < 4; ++r) {
            if (lo == 0) LS[w][hi * 4 + r] = ls[r];
#pragma unroll
            for (int dg = 0; dg < 4; ++dg) OA[w][hi * 4 + r][dg * 16 + lo] = acc[dg][r];
        }
        __syncthreads();

        // ---- merge: plain sums over the 8 waves ----
        {
            const int row = t >> 5, c0 = (t & 31) * 2;
            float s0 = 0.f, s1 = 0.f, Lt = 0.f;
#pragma unroll
            for (int wv = 0; wv < 8; ++wv) {
                s0 += OA[wv][row][c0];
                s1 += OA[wv][row][c0 + 1];
                Lt += LS[wv][row];
            }
            const float inv = 0.125f / Lt;
            float2 o = make_float2(s0 * inv, s1 * inv);
            *(float2*)(out + ((size_t)b * 2048 + q0 + row) * 64 + c0) = o;
        }
        __syncthreads();   // protect OA/LS reuse by next phase
    }
}

extern "C" void kernel_launch(void* const* d_in, const int* in_sizes, int n_in,
                              void* d_out, int out_size, void* d_ws, size_t ws_size,
                              hipStream_t stream) {
    const float* x  = (const float*)d_in[0];
    const float* Wq = (const float*)d_in[1];
    const float* Wk = (const float*)d_in[2];
    const float* Wv = (const float*)d_in[3];
    float* outp = (float*)d_out;

    u16* Wt2 = (u16*)d_ws;               // 16*48*512 = 393216 u16 (768 KB)
    u16* Qhi = Wt2 + 393216;             // 8192*64 each
    u16* Qlo = Qhi + 524288;
    u16* Khi = Qlo + 524288;
    u16* Klo = Khi + 524288;
    u16* Vt  = Klo + 524288;             // [4][64][2048]

    wtrans_kernel<<<dim3(192), dim3(128), 0, stream>>>(Wq, Wk, Wv, Wt2);
    proj_kernel<<<dim3(256), dim3(512), 0, stream>>>(x, Wt2, Qhi, Qlo, Khi, Klo, Vt);
    attn_kernel<<<dim3(64, 4), dim3(512), 0, stream>>>(Qhi, Qlo, Khi, Klo, Vt, outp);
}